// Round 8
// baseline (74.343 us; speedup 1.0000x reference)
//
#include <hip/hip_runtime.h>

// MoE B=4096, D=256, H=1024, E=8. 2 launches:
//  K1 prep (1032 blocks): 0..511 W1->w1t[e][h][d] bf16; 512..1023 W2->w2b[e][hc][d][64] bf16
//                         (h-blocked for contiguous gemm2 staging); 1024..1031 deterministic bin.
//  K2 fused (256 blocks): block=(e, 32-token tile). Full MLP per tile: loop 16 h-chunks of 64:
//     stage w1/w2 chunk (reg-prefetched one chunk ahead), gemm1 MFMA + relu -> ht (LDS),
//     gemm2 MFMA accumulate y in regs; scatter-out epilogue. No hw intermediate.
//     Raw s_barrier + lgkmcnt-only waits so the vmcnt prefetch stays in flight.
//  R7 bug fixed: LDS stores now slot-linear (the rotated store permuted data; rule-20
//  prevents the register-side rotation, so rotation is dropped entirely).

#define D_DIM 256
#define H_DIM 1024
#define E_NUM 8
#define B_TOK 4096
#define CAP   1024
#define NCH   16      // H chunks of 64

typedef __attribute__((ext_vector_type(8))) short short8;
typedef __attribute__((ext_vector_type(4))) float f32x4;
typedef unsigned short u16;
typedef unsigned int u32;
typedef unsigned long long u64;

// ws layout (bytes)
#define CNT_OFF    0
#define BUCKET_OFF 1024
#define W1T_OFF    (BUCKET_OFF + E_NUM*B_TOK*4)
#define W2B_OFF    (W1T_OFF + (size_t)E_NUM*H_DIM*D_DIM*2)

__device__ __forceinline__ u16 f2bf(float f) {
    u32 u = __builtin_bit_cast(u32, f);
    u = (u + 0x7fffu + ((u >> 16) & 1u)) >> 16;  // RNE
    return (u16)u;
}

// 64x64 fp32->bf16 transpose tile: reads in[(rt*64+r)*C + ct*64+c] into tile[r][c].
__device__ __forceinline__ void trans_load(const float* __restrict__ in, int C,
                                           int rt, int ct, int tt, u16* tile) {
    #pragma unroll
    for (int it = 0; it < 4; ++it) {
        int r = it * 16 + (tt >> 4);
        int c4 = (tt & 15) * 4;
        float4 v = *(const float4*)(in + (size_t)(rt * 64 + r) * C + ct * 64 + c4);
        u64 pk = (u64)f2bf(v.x) | ((u64)f2bf(v.y) << 16)
               | ((u64)f2bf(v.z) << 32) | ((u64)f2bf(v.w) << 48);
        *(u64*)&tile[r * 68 + c4] = pk;
    }
}

__device__ __forceinline__ uint4 trans_pack(const u16* tile, int oc, int r0) {
    u32 p0 = tile[(r0 + 0) * 68 + oc] | ((u32)tile[(r0 + 1) * 68 + oc] << 16);
    u32 p1 = tile[(r0 + 2) * 68 + oc] | ((u32)tile[(r0 + 3) * 68 + oc] << 16);
    u32 p2 = tile[(r0 + 4) * 68 + oc] | ((u32)tile[(r0 + 5) * 68 + oc] << 16);
    u32 p3 = tile[(r0 + 6) * 68 + oc] | ((u32)tile[(r0 + 7) * 68 + oc] << 16);
    return uint4{p0, p1, p2, p3};
}

// ---- K1: prep = W1 transpose | W2 blocked transpose | bin ----
__global__ __launch_bounds__(256) void prep_kernel(
    const float* __restrict__ W1, const float* __restrict__ W2,
    const int* __restrict__ eidx,
    int* __restrict__ cnt, int* __restrict__ bucket,
    u16* __restrict__ w1t, u16* __restrict__ w2b)
{
    __shared__ u16 tile[64 * 68];
    const int b = blockIdx.x, tid = threadIdx.x;
    if (b < 512) {                       // W1 [256d][1024h] -> w1t[e][h][d]
        int e = b >> 6, tj = b & 63;
        int rt = tj >> 4, ct = tj & 15;  // rt over D/64, ct over H/64
        trans_load(W1 + (size_t)e * D_DIM * H_DIM, H_DIM, rt, ct, tid, tile);
        __syncthreads();
        u16* outp = w1t + (size_t)e * H_DIM * D_DIM;
        #pragma unroll
        for (int it = 0; it < 2; ++it) {
            int oc = it * 32 + (tid >> 3);
            int r0 = (tid & 7) * 8;
            *(uint4*)(outp + (size_t)(ct * 64 + oc) * D_DIM + rt * 64 + r0) =
                trans_pack(tile, oc, r0);
        }
    } else if (b < 1024) {               // W2 [1024h][256d] -> w2b[e][hc][d][64h]
        int e = (b - 512) >> 6, tj = (b - 512) & 63;
        int rt = tj >> 2, ct = tj & 3;   // rt over H/64 (= chunk), ct over D/64
        trans_load(W2 + (size_t)e * H_DIM * D_DIM, D_DIM, rt, ct, tid, tile);
        __syncthreads();
        u16* outp = w2b + (size_t)e * D_DIM * H_DIM + (size_t)rt * (D_DIM * 64);
        #pragma unroll
        for (int it = 0; it < 2; ++it) {
            int oc = it * 32 + (tid >> 3);     // d-local
            int r0 = (tid & 7) * 8;            // h-local
            *(uint4*)(outp + (size_t)(ct * 64 + oc) * 64 + r0) =
                trans_pack(tile, oc, r0);
        }
    } else {                             // bin: block per expert, deterministic scan
        __shared__ int wsum[4];
        const int e = b - 1024;
        const int lane = tid & 63, wv = tid >> 6;
        int base = 0;
        #pragma unroll
        for (int c = 0; c < 16; ++c) {
            int t = c * 256 + tid;
            bool m = (eidx[t] == e);
            u64 bal = __ballot(m);
            int pfx = __popcll(bal & ((1ull << lane) - 1ull));
            if (lane == 0) wsum[wv] = __popcll(bal);
            __syncthreads();
            int wb = 0, total = 0;
            #pragma unroll
            for (int i = 0; i < 4; ++i) { if (i < wv) wb += wsum[i]; total += wsum[i]; }
            if (m) bucket[e * B_TOK + base + wb + pfx] = t;
            base += total;
            __syncthreads();
        }
        if (tid == 0) cnt[e] = base;
    }
}

// ---- K2: fused MLP. Block = (e, 32-token tile). ----
__global__ __launch_bounds__(256, 1) void moe_fused(
    const float* __restrict__ x, const u16* __restrict__ w1t,
    const u16* __restrict__ w2b, const float* __restrict__ b1,
    const float* __restrict__ b2, const int* __restrict__ cnt,
    const int* __restrict__ bucket, float* __restrict__ out)
{
    __shared__ u16 xs[32 * 264];    // 16896 B  x tile bf16 [m][d]
    __shared__ u16 w1s[64 * 264];   // 33792 B  W1 chunk [h][d]
    __shared__ u16 w2s[256 * 72];   // 36864 B  W2 chunk [d][h]
    __shared__ u16 ht[32 * 72];     //  4608 B  h tile [m][h]   (total 92 KB)

    const int bid = blockIdx.x;
    const int e = bid >> 5, tile = bid & 31;
    const int n = min(cnt[e], CAP);
    const int row0 = tile * 32;
    if (row0 >= n) return;

    const int tid = threadIdx.x;
    const int w = tid >> 6, L = tid & 63, l15 = L & 15, l4 = L >> 4;

    const u16* gw1 = w1t + (size_t)e * H_DIM * D_DIM;
    const u16* gw2 = w2b + (size_t)e * D_DIM * H_DIM;

    // ---- stage x tile (once): row = tid/8, 8 threads cover 256 floats
    {
        int row = tid >> 3, sub = tid & 7;
        bool valid = (row0 + row) < n;
        int token = valid ? bucket[e * B_TOK + row0 + row] : 0;
        const float* src = x + (size_t)token * D_DIM + sub * 32;
        #pragma unroll
        for (int i = 0; i < 8; ++i) {
            float4 v = valid ? *(const float4*)(src + i * 4) : float4{0.f, 0.f, 0.f, 0.f};
            u64 pk = (u64)f2bf(v.x) | ((u64)f2bf(v.y) << 16)
                   | ((u64)f2bf(v.z) << 32) | ((u64)f2bf(v.w) << 48);
            *(u64*)&xs[row * 264 + sub * 32 + i * 4] = pk;
        }
    }

    // ---- prefetch chunk 0 weight regs (32 KB w1 + 32 KB w2, 128 B/thread each)
    short8 w1r[8], w2r[8];
    #pragma unroll
    for (int i = 0; i < 8; ++i) w1r[i] = *(const short8*)(gw1 + tid * 64 + i * 8);
    #pragma unroll
    for (int i = 0; i < 8; ++i) w2r[i] = *(const short8*)(gw2 + tid * 64 + i * 8);

    f32x4 acc2[2][4];
    #pragma unroll
    for (int mf = 0; mf < 2; ++mf)
        #pragma unroll
        for (int nf = 0; nf < 4; ++nf) acc2[mf][nf] = (f32x4){0.f, 0.f, 0.f, 0.f};

    const int w1row = tid >> 2, w1dq = tid & 3;

    for (int jc = 0; jc < NCH; ++jc) {
        // wait for prefetched regs, then place into LDS (slot-linear: data i -> slot i)
        asm volatile("s_waitcnt vmcnt(0)" ::: "memory");
        #pragma unroll
        for (int i = 0; i < 8; ++i)
            *(short8*)&w1s[w1row * 264 + w1dq * 64 + i * 8] = w1r[i];
        #pragma unroll
        for (int i = 0; i < 8; ++i)
            *(short8*)&w2s[tid * 72 + i * 8] = w2r[i];
        // issue next chunk's loads (stay in flight across barriers)
        if (jc + 1 < NCH) {
            const u16* s1 = gw1 + (jc + 1) * (64 * D_DIM) + tid * 64;
            const u16* s2 = gw2 + (jc + 1) * (D_DIM * 64) + tid * 64;
            #pragma unroll
            for (int i = 0; i < 8; ++i) w1r[i] = *(const short8*)(s1 + i * 8);
            #pragma unroll
            for (int i = 0; i < 8; ++i) w2r[i] = *(const short8*)(s2 + i * 8);
        }
        asm volatile("s_waitcnt lgkmcnt(0)" ::: "memory");
        __builtin_amdgcn_s_barrier();

        // ---- gemm1: h[32][64] = xs[32][256] @ w1chunk^T, wave w owns h-cols w*16..+16
        f32x4 acc1[2];
        acc1[0] = (f32x4){0.f, 0.f, 0.f, 0.f};
        acc1[1] = (f32x4){0.f, 0.f, 0.f, 0.f};
        #pragma unroll
        for (int k = 0; k < 8; ++k) {
            short8 bfr = *(const short8*)&w1s[(w * 16 + l15) * 264 + k * 32 + l4 * 8];
            short8 a0 = *(const short8*)&xs[l15 * 264 + k * 32 + l4 * 8];
            short8 a1 = *(const short8*)&xs[(16 + l15) * 264 + k * 32 + l4 * 8];
            acc1[0] = __builtin_amdgcn_mfma_f32_16x16x32_bf16(a0, bfr, acc1[0], 0, 0, 0);
            acc1[1] = __builtin_amdgcn_mfma_f32_16x16x32_bf16(a1, bfr, acc1[1], 0, 0, 0);
        }
        {
            float bias = b1[e * H_DIM + jc * 64 + w * 16 + l15];
            #pragma unroll
            for (int mf = 0; mf < 2; ++mf)
                #pragma unroll
                for (int jj = 0; jj < 4; ++jj) {
                    float v = fmaxf(acc1[mf][jj] + bias, 0.f);
                    ht[(mf * 16 + l4 * 4 + jj) * 72 + w * 16 + l15] = f2bf(v);
                }
        }
        asm volatile("s_waitcnt lgkmcnt(0)" ::: "memory");
        __builtin_amdgcn_s_barrier();

        // ---- gemm2: y[32][256] += ht[32][64] @ w2chunk, wave w owns d-cols w*64..+64
        #pragma unroll
        for (int ks = 0; ks < 2; ++ks) {
            short8 a20 = *(const short8*)&ht[l15 * 72 + ks * 32 + l4 * 8];
            short8 a21 = *(const short8*)&ht[(16 + l15) * 72 + ks * 32 + l4 * 8];
            #pragma unroll
            for (int nf = 0; nf < 4; ++nf) {
                short8 bf2 = *(const short8*)&w2s[(w * 64 + nf * 16 + l15) * 72 + ks * 32 + l4 * 8];
                acc2[0][nf] = __builtin_amdgcn_mfma_f32_16x16x32_bf16(a20, bf2, acc2[0][nf], 0, 0, 0);
                acc2[1][nf] = __builtin_amdgcn_mfma_f32_16x16x32_bf16(a21, bf2, acc2[1][nf], 0, 0, 0);
            }
        }
        asm volatile("s_waitcnt lgkmcnt(0)" ::: "memory");
        __builtin_amdgcn_s_barrier();   // all reads done before next chunk's ds_writes
    }

    // ---- epilogue: scatter out[token][d] = y + b2
    #pragma unroll
    for (int mf = 0; mf < 2; ++mf)
        #pragma unroll
        for (int jj = 0; jj < 4; ++jj) {
            int m = mf * 16 + l4 * 4 + jj;
            if (row0 + m < n) {
                int token = bucket[e * B_TOK + row0 + m];
                #pragma unroll
                for (int nf = 0; nf < 4; ++nf) {
                    int d = w * 64 + nf * 16 + l15;
                    out[(size_t)token * D_DIM + d] = acc2[mf][nf][jj] + b2[e * D_DIM + d];
                }
            }
        }
}

extern "C" void kernel_launch(void* const* d_in, const int* in_sizes, int n_in,
                              void* d_out, int out_size, void* d_ws, size_t ws_size,
                              hipStream_t stream) {
    const float* x  = (const float*)d_in[0];
    const float* W1 = (const float*)d_in[1];
    const float* b1 = (const float*)d_in[2];
    const float* W2 = (const float*)d_in[3];
    const float* b2 = (const float*)d_in[4];
    const int* eidx = (const int*)d_in[5];
    float* out = (float*)d_out;

    char* ws = (char*)d_ws;
    int* cnt    = (int*)(ws + CNT_OFF);
    int* bucket = (int*)(ws + BUCKET_OFF);
    u16* w1t    = (u16*)(ws + W1T_OFF);
    u16* w2b    = (u16*)(ws + W2B_OFF);

    prep_kernel<<<1032, 256, 0, stream>>>(W1, W2, eidx, cnt, bucket, w1t, w2b);
    moe_fused<<<E_NUM * 32, 256, 0, stream>>>(x, w1t, w2b, b1, b2, cnt, bucket, out);
}

// Round 9
// 45.796 us; speedup vs baseline: 1.6234x; 1.6234x over previous
//
#include <hip/hip_runtime.h>

// MoE B=4096, D=256, H=1024, E=8. 3 launches (R5 high-TLP structure + staging upgrade):
//  K1 prep (1288 blocks): 0..511 W1->w1t[e][h][d] bf16; 512..1023 W2->w2t[e][d][h] bf16;
//     1024..1279 x->xb[token][d] bf16 (no gather -> independent of bin); 1280..1287 bin.
//  K2 gemm1 (2048 blocks): stage xs (bucket-gather from xb) + w1s via global_load_lds
//     with XOR-swizzled source; h = relu(x@W1+b1) -> hw bf16.
//  K3 gemm2 (512 blocks): same staging technique; out[token] = h@W2 + b2 scatter.
// Swizzle (rule 21, both-sides): LDS dest linear; source col ^= (row&7)<<4; ds_read
// applies the same XOR. Residual 2-way conflict is free (m136).

#define D_DIM 256
#define H_DIM 1024
#define E_NUM 8
#define B_TOK 4096
#define CAP   1024

typedef __attribute__((ext_vector_type(8))) short short8;
typedef __attribute__((ext_vector_type(4))) float f32x4;
typedef unsigned short u16;
typedef unsigned int u32;
typedef unsigned long long u64;

// ws layout (bytes)
#define CNT_OFF    0
#define BUCKET_OFF 1024
#define XB_OFF     (BUCKET_OFF + E_NUM*B_TOK*4)
#define W1T_OFF    (XB_OFF  + (size_t)B_TOK*D_DIM*2)
#define W2T_OFF    (W1T_OFF + (size_t)E_NUM*H_DIM*D_DIM*2)
#define HW_OFF     (W2T_OFF + (size_t)E_NUM*D_DIM*H_DIM*2)

__device__ __forceinline__ u16 f2bf(float f) {
    u32 u = __builtin_bit_cast(u32, f);
    u = (u + 0x7fffu + ((u >> 16) & 1u)) >> 16;  // RNE
    return (u16)u;
}

__device__ __forceinline__ void gload16(const void* g, void* l) {
    __builtin_amdgcn_global_load_lds(
        (const __attribute__((address_space(1))) unsigned int*)g,
        (__attribute__((address_space(3))) unsigned int*)l, 16, 0, 0);
}

// 64x64 fp32->bf16 transpose tile helpers (proven R5)
__device__ __forceinline__ void trans_load(const float* __restrict__ in, int C,
                                           int rt, int ct, int tt, u16* tile) {
    #pragma unroll
    for (int it = 0; it < 4; ++it) {
        int r = it * 16 + (tt >> 4);
        int c4 = (tt & 15) * 4;
        float4 v = *(const float4*)(in + (size_t)(rt * 64 + r) * C + ct * 64 + c4);
        u64 pk = (u64)f2bf(v.x) | ((u64)f2bf(v.y) << 16)
               | ((u64)f2bf(v.z) << 32) | ((u64)f2bf(v.w) << 48);
        *(u64*)&tile[r * 68 + c4] = pk;
    }
}

__device__ __forceinline__ uint4 trans_pack(const u16* tile, int oc, int r0) {
    u32 p0 = tile[(r0 + 0) * 68 + oc] | ((u32)tile[(r0 + 1) * 68 + oc] << 16);
    u32 p1 = tile[(r0 + 2) * 68 + oc] | ((u32)tile[(r0 + 3) * 68 + oc] << 16);
    u32 p2 = tile[(r0 + 4) * 68 + oc] | ((u32)tile[(r0 + 5) * 68 + oc] << 16);
    u32 p3 = tile[(r0 + 6) * 68 + oc] | ((u32)tile[(r0 + 7) * 68 + oc] << 16);
    return uint4{p0, p1, p2, p3};
}

// ---- K1: prep = W1 trans | W2 trans | x convert | bin (all independent) ----
__global__ __launch_bounds__(256) void prep_kernel(
    const float* __restrict__ x, const float* __restrict__ W1,
    const float* __restrict__ W2, const int* __restrict__ eidx,
    int* __restrict__ cnt, int* __restrict__ bucket,
    u16* __restrict__ xb, u16* __restrict__ w1t, u16* __restrict__ w2t)
{
    __shared__ u16 tile[64 * 68];
    const int b = blockIdx.x, tid = threadIdx.x;
    if (b < 512) {                       // W1 [256d][1024h] -> w1t[e][h][d]
        int e = b >> 6, tj = b & 63;
        int rt = tj >> 4, ct = tj & 15;
        trans_load(W1 + (size_t)e * D_DIM * H_DIM, H_DIM, rt, ct, tid, tile);
        __syncthreads();
        u16* outp = w1t + (size_t)e * H_DIM * D_DIM;
        #pragma unroll
        for (int it = 0; it < 2; ++it) {
            int oc = it * 32 + (tid >> 3);
            int r0 = (tid & 7) * 8;
            *(uint4*)(outp + (size_t)(ct * 64 + oc) * D_DIM + rt * 64 + r0) =
                trans_pack(tile, oc, r0);
        }
    } else if (b < 1024) {               // W2 [1024h][256d] -> w2t[e][d][h]
        int e = (b - 512) >> 6, tj = (b - 512) & 63;
        int rt = tj >> 2, ct = tj & 3;   // rt over H/64, ct over D/64
        trans_load(W2 + (size_t)e * H_DIM * D_DIM, D_DIM, rt, ct, tid, tile);
        __syncthreads();
        u16* outp = w2t + (size_t)e * D_DIM * H_DIM;
        #pragma unroll
        for (int it = 0; it < 2; ++it) {
            int oc = it * 32 + (tid >> 3);
            int r0 = (tid & 7) * 8;
            *(uint4*)(outp + (size_t)(ct * 64 + oc) * H_DIM + rt * 64 + r0) =
                trans_pack(tile, oc, r0);
        }
    } else if (b < 1280) {               // x fp32 -> xb bf16, token order (no bucket)
        int gb = b - 1024;               // 256 blocks x 16 rows
        int row = gb * 16 + (tid >> 4);
        int sub = tid & 15;
        const float* src = x + (size_t)row * D_DIM + sub * 16;
        u16* dst = xb + (size_t)row * D_DIM + sub * 16;
        #pragma unroll
        for (int i = 0; i < 4; ++i) {
            float4 v = *(const float4*)(src + i * 4);
            u64 pk = (u64)f2bf(v.x) | ((u64)f2bf(v.y) << 16)
                   | ((u64)f2bf(v.z) << 32) | ((u64)f2bf(v.w) << 48);
            *(u64*)(dst + i * 4) = pk;
        }
    } else {                             // bin: block per expert, deterministic scan
        __shared__ int wsum[4];
        const int e = b - 1280;
        const int lane = tid & 63, wv = tid >> 6;
        int base = 0;
        #pragma unroll
        for (int c = 0; c < 16; ++c) {
            int t = c * 256 + tid;
            bool m = (eidx[t] == e);
            u64 bal = __ballot(m);
            int pfx = __popcll(bal & ((1ull << lane) - 1ull));
            if (lane == 0) wsum[wv] = __popcll(bal);
            __syncthreads();
            int wb = 0, total = 0;
            #pragma unroll
            for (int i = 0; i < 4; ++i) { if (i < wv) wb += wsum[i]; total += wsum[i]; }
            if (m) bucket[e * B_TOK + base + wb + pfx] = t;
            base += total;
            __syncthreads();
        }
        if (tid == 0) cnt[e] = base;
    }
}

// ---- K2: GEMM1  M=64,N=64,K=256. gload_lds + swizzled staging. ----
__global__ __launch_bounds__(256, 2) void gemm1_kernel(
    const u16* __restrict__ xb, const u16* __restrict__ w1t,
    const float* __restrict__ b1, const int* __restrict__ cnt,
    const int* __restrict__ bucket, u16* __restrict__ hw)
{
    __shared__ u16 xs[64 * 256];    // 32 KB, unpadded (swizzled)
    __shared__ u16 w1s[64 * 256];   // 32 KB
    __shared__ u16 hs[64 * 72];     //  9 KB  (73 KB total -> 2 blocks/CU)

    const int b = blockIdx.x;
    const int e = b >> 8, tile = (b >> 4) & 15, hch = b & 15;
    const int n = min(cnt[e], CAP);
    const int row0 = tile * 64;
    if (row0 >= n) return;

    const int tid = threadIdx.x;
    const int wv = tid >> 6, ln = tid & 63;
    const int l15 = ln & 15, l4 = ln >> 4;
    const int wr = (wv >> 1) * 32, wc = (wv & 1) * 32;

    // stage xs (gather via bucket) + w1s; LDS dest linear, source col XOR-swizzled
    {
        const char* gw = (const char*)(w1t + ((size_t)e * H_DIM + hch * 64) * D_DIM);
        const char* gx = (const char*)xb;
        #pragma unroll
        for (int i = 0; i < 8; ++i) {
            int p = wv * 8192 + i * 1024 + ln * 16;        // dest byte offset
            int row = p >> 9;
            int cb = (p & 511) ^ ((row & 7) << 4);
            int grow = row0 + row;
            int token = grow < n ? bucket[e * B_TOK + grow] : 0;  // clamp: finite garbage, stores guarded
            gload16(gx + (size_t)token * 512 + cb, (char*)xs + p);
            gload16(gw + (size_t)row * 512 + cb, (char*)w1s + p);
        }
    }
    __syncthreads();   // drains vmcnt -> staged data visible

    f32x4 acc[2][2];
    #pragma unroll
    for (int i = 0; i < 2; ++i)
        #pragma unroll
        for (int j = 0; j < 2; ++j) acc[i][j] = (f32x4){0.f, 0.f, 0.f, 0.f};

    #pragma unroll
    for (int k = 0; k < 8; ++k) {
        int cbk = k * 64 + l4 * 16;
        int ra = wr + l15, rb = wc + l15;
        short8 a0 = *(const short8*)((const char*)xs + (((ra)      * 512 + cbk) ^ ((ra & 7) << 4)));
        short8 a1 = *(const short8*)((const char*)xs + (((ra + 16) * 512 + cbk) ^ ((ra & 7) << 4)));
        short8 b0 = *(const short8*)((const char*)w1s + (((rb)      * 512 + cbk) ^ ((rb & 7) << 4)));
        short8 b1v = *(const short8*)((const char*)w1s + (((rb + 16) * 512 + cbk) ^ ((rb & 7) << 4)));
        acc[0][0] = __builtin_amdgcn_mfma_f32_16x16x32_bf16(a0, b0, acc[0][0], 0, 0, 0);
        acc[0][1] = __builtin_amdgcn_mfma_f32_16x16x32_bf16(a0, b1v, acc[0][1], 0, 0, 0);
        acc[1][0] = __builtin_amdgcn_mfma_f32_16x16x32_bf16(a1, b0, acc[1][0], 0, 0, 0);
        acc[1][1] = __builtin_amdgcn_mfma_f32_16x16x32_bf16(a1, b1v, acc[1][1], 0, 0, 0);
    }

    #pragma unroll
    for (int mr = 0; mr < 2; ++mr)
        #pragma unroll
        for (int nc = 0; nc < 2; ++nc) {
            float bias = b1[e * H_DIM + hch * 64 + wc + nc * 16 + l15];
            #pragma unroll
            for (int j = 0; j < 4; ++j) {
                float v = fmaxf(acc[mr][nc][j] + bias, 0.f);
                hs[(wr + mr * 16 + l4 * 4 + j) * 72 + wc + nc * 16 + l15] = f2bf(v);
            }
        }
    __syncthreads();
    {
        u16* gh = hw + ((size_t)e * CAP + row0) * H_DIM + hch * 64;
        int rr8 = tid >> 3, off = (tid & 7) * 8;
        #pragma unroll
        for (int it = 0; it < 2; ++it) {
            int row = it * 32 + rr8;
            *(short8*)&gh[(size_t)row * H_DIM + off] = *(const short8*)&hs[row * 72 + off];
        }
    }
}

// ---- K3: GEMM2  M=64,N=64,K=1024 (4 chunks). gload_lds + swizzled staging. ----
__global__ __launch_bounds__(256, 2) void gemm2_kernel(
    const u16* __restrict__ hw, const u16* __restrict__ w2t,
    const float* __restrict__ b2, const int* __restrict__ cnt,
    const int* __restrict__ bucket, float* __restrict__ out)
{
    __shared__ u16 as_[64 * 256];   // 32 KB
    __shared__ u16 bs[64 * 256];    // 32 KB  (64 KB -> 2 blocks/CU)

    const int b = blockIdx.x;
    const int e = b >> 6, tile = (b >> 2) & 15, nch = b & 3;
    const int n = min(cnt[e], CAP);
    if (tile * 64 >= n) return;

    const int tid = threadIdx.x;
    const int wv = tid >> 6, ln = tid & 63;
    const int l15 = ln & 15, l4 = ln >> 4;
    const int wr = (wv >> 1) * 32, wc = (wv & 1) * 32;

    f32x4 acc[2][2];
    #pragma unroll
    for (int i = 0; i < 2; ++i)
        #pragma unroll
        for (int j = 0; j < 2; ++j) acc[i][j] = (f32x4){0.f, 0.f, 0.f, 0.f};

    const char* ga = (const char*)(hw + ((size_t)e * CAP + tile * 64) * H_DIM);   // 2048 B rows
    const char* gb_ = (const char*)(w2t + ((size_t)e * D_DIM + nch * 64) * H_DIM);

    for (int kc = 0; kc < 4; ++kc) {
        __syncthreads();   // prior iteration's LDS reads complete
        #pragma unroll
        for (int i = 0; i < 8; ++i) {
            int p = wv * 8192 + i * 1024 + ln * 16;
            int row = p >> 9;
            int cb = (p & 511) ^ ((row & 7) << 4);
            gload16(ga + (size_t)row * 2048 + kc * 512 + cb, (char*)as_ + p);
            gload16(gb_ + (size_t)row * 2048 + kc * 512 + cb, (char*)bs + p);
        }
        __syncthreads();   // drains vmcnt -> staged data visible

        #pragma unroll
        for (int k = 0; k < 8; ++k) {
            int cbk = k * 64 + l4 * 16;
            int ra = wr + l15, rb = wc + l15;
            short8 a0 = *(const short8*)((const char*)as_ + (((ra)      * 512 + cbk) ^ ((ra & 7) << 4)));
            short8 a1 = *(const short8*)((const char*)as_ + (((ra + 16) * 512 + cbk) ^ ((ra & 7) << 4)));
            short8 b0 = *(const short8*)((const char*)bs + (((rb)      * 512 + cbk) ^ ((rb & 7) << 4)));
            short8 b1v = *(const short8*)((const char*)bs + (((rb + 16) * 512 + cbk) ^ ((rb & 7) << 4)));
            acc[0][0] = __builtin_amdgcn_mfma_f32_16x16x32_bf16(a0, b0, acc[0][0], 0, 0, 0);
            acc[0][1] = __builtin_amdgcn_mfma_f32_16x16x32_bf16(a0, b1v, acc[0][1], 0, 0, 0);
            acc[1][0] = __builtin_amdgcn_mfma_f32_16x16x32_bf16(a1, b0, acc[1][0], 0, 0, 0);
            acc[1][1] = __builtin_amdgcn_mfma_f32_16x16x32_bf16(a1, b1v, acc[1][1], 0, 0, 0);
        }
    }

    #pragma unroll
    for (int mr = 0; mr < 2; ++mr)
        #pragma unroll
        for (int jj = 0; jj < 4; ++jj) {
            int m = wr + mr * 16 + l4 * 4 + jj;
            if (tile * 64 + m < n) {
                int token = bucket[e * B_TOK + tile * 64 + m];
                #pragma unroll
                for (int nc = 0; nc < 2; ++nc) {
                    int d = nch * 64 + wc + nc * 16 + l15;
                    out[(size_t)token * D_DIM + d] = acc[mr][nc][jj] + b2[e * D_DIM + d];
                }
            }
        }
}

extern "C" void kernel_launch(void* const* d_in, const int* in_sizes, int n_in,
                              void* d_out, int out_size, void* d_ws, size_t ws_size,
                              hipStream_t stream) {
    const float* x  = (const float*)d_in[0];
    const float* W1 = (const float*)d_in[1];
    const float* b1 = (const float*)d_in[2];
    const float* W2 = (const float*)d_in[3];
    const float* b2 = (const float*)d_in[4];
    const int* eidx = (const int*)d_in[5];
    float* out = (float*)d_out;

    char* ws = (char*)d_ws;
    int* cnt    = (int*)(ws + CNT_OFF);
    int* bucket = (int*)(ws + BUCKET_OFF);
    u16* xb     = (u16*)(ws + XB_OFF);
    u16* w1t    = (u16*)(ws + W1T_OFF);
    u16* w2t    = (u16*)(ws + W2T_OFF);
    u16* hw     = (u16*)(ws + HW_OFF);

    prep_kernel<<<1288, 256, 0, stream>>>(x, W1, W2, eidx, cnt, bucket, xb, w1t, w2t);
    gemm1_kernel<<<E_NUM * 16 * 16, 256, 0, stream>>>(xb, w1t, b1, cnt, bucket, hw);
    gemm2_kernel<<<E_NUM * 16 * 4, 256, 0, stream>>>(hw, w2t, b2, cnt, bucket, out);
}

// Round 10
// 41.669 us; speedup vs baseline: 1.7841x; 1.0990x over previous
//
#include <hip/hip_runtime.h>

// MoE B=4096, D=256, H=1024, E=8. 3 launches (R5-proven gemms + merged prep):
//  K1 prep (1288 blocks): 0..7 bin (FIRST - longest job); 8..263 x->xb bf16;
//     264..775 W1->w1t[e][h][d] bf16; 776..1287 W2->w2t[e][d][h] bf16.
//  K2 gemm1 (2048 blocks): R5 padded reg-staging; x gathered from xb via bucket
//     (token indices hoisted before staging loop). h=relu(x@W1+b1) -> hw bf16.
//  K3 gemm2 (512 blocks): R5 verbatim. out[token] = h@W2 + b2 scatter.

#define D_DIM 256
#define H_DIM 1024
#define E_NUM 8
#define B_TOK 4096
#define CAP   1024

typedef __attribute__((ext_vector_type(8))) short short8;
typedef __attribute__((ext_vector_type(4))) float f32x4;
typedef unsigned short u16;
typedef unsigned int u32;
typedef unsigned long long u64;

// ws layout (bytes)
#define CNT_OFF    0
#define BUCKET_OFF 1024
#define XB_OFF     (BUCKET_OFF + E_NUM*B_TOK*4)
#define W1T_OFF    (XB_OFF  + (size_t)B_TOK*D_DIM*2)
#define W2T_OFF    (W1T_OFF + (size_t)E_NUM*H_DIM*D_DIM*2)
#define HW_OFF     (W2T_OFF + (size_t)E_NUM*D_DIM*H_DIM*2)

__device__ __forceinline__ u16 f2bf(float f) {
    u32 u = __builtin_bit_cast(u32, f);
    u = (u + 0x7fffu + ((u >> 16) & 1u)) >> 16;  // RNE
    return (u16)u;
}

// 64x64 fp32->bf16 transpose tile (256 threads, 1 internal sync)
__device__ __forceinline__ void trans_load(const float* __restrict__ in, int C,
                                           int rt, int ct, int tt, u16* tile) {
    #pragma unroll
    for (int it = 0; it < 4; ++it) {
        int r = it * 16 + (tt >> 4);
        int c4 = (tt & 15) * 4;
        float4 v = *(const float4*)(in + (size_t)(rt * 64 + r) * C + ct * 64 + c4);
        u64 pk = (u64)f2bf(v.x) | ((u64)f2bf(v.y) << 16)
               | ((u64)f2bf(v.z) << 32) | ((u64)f2bf(v.w) << 48);
        *(u64*)&tile[r * 68 + c4] = pk;
    }
}

__device__ __forceinline__ uint4 trans_pack(const u16* tile, int oc, int r0) {
    u32 p0 = tile[(r0 + 0) * 68 + oc] | ((u32)tile[(r0 + 1) * 68 + oc] << 16);
    u32 p1 = tile[(r0 + 2) * 68 + oc] | ((u32)tile[(r0 + 3) * 68 + oc] << 16);
    u32 p2 = tile[(r0 + 4) * 68 + oc] | ((u32)tile[(r0 + 5) * 68 + oc] << 16);
    u32 p3 = tile[(r0 + 6) * 68 + oc] | ((u32)tile[(r0 + 7) * 68 + oc] << 16);
    return uint4{p0, p1, p2, p3};
}

// ---- K1: prep = bin (first!) | x convert | W1 trans | W2 trans ----
__global__ __launch_bounds__(256) void prep_kernel(
    const float* __restrict__ x, const float* __restrict__ W1,
    const float* __restrict__ W2, const int* __restrict__ eidx,
    int* __restrict__ cnt, int* __restrict__ bucket,
    u16* __restrict__ xb, u16* __restrict__ w1t, u16* __restrict__ w2t)
{
    __shared__ u16 tile[64 * 68];
    const int b = blockIdx.x, tid = threadIdx.x;
    if (b < 8) {                         // bin: block per expert, deterministic scan
        __shared__ int wsum[4];
        const int e = b;
        const int lane = tid & 63, wv = tid >> 6;
        int base = 0;
        #pragma unroll
        for (int c = 0; c < 16; ++c) {
            int t = c * 256 + tid;
            bool m = (eidx[t] == e);
            u64 bal = __ballot(m);
            int pfx = __popcll(bal & ((1ull << lane) - 1ull));
            if (lane == 0) wsum[wv] = __popcll(bal);
            __syncthreads();
            int wb = 0, total = 0;
            #pragma unroll
            for (int i = 0; i < 4; ++i) { if (i < wv) wb += wsum[i]; total += wsum[i]; }
            if (m) bucket[e * B_TOK + base + wb + pfx] = t;
            base += total;
            __syncthreads();
        }
        if (tid == 0) cnt[e] = base;
    } else if (b < 264) {                // x fp32 -> xb bf16, token order
        int gb = b - 8;                  // 256 blocks x 16 rows
        int row = gb * 16 + (tid >> 4);
        int sub = tid & 15;
        const float* src = x + (size_t)row * D_DIM + sub * 16;
        u16* dst = xb + (size_t)row * D_DIM + sub * 16;
        #pragma unroll
        for (int i = 0; i < 4; ++i) {
            float4 v = *(const float4*)(src + i * 4);
            u64 pk = (u64)f2bf(v.x) | ((u64)f2bf(v.y) << 16)
                   | ((u64)f2bf(v.z) << 32) | ((u64)f2bf(v.w) << 48);
            *(u64*)(dst + i * 4) = pk;
        }
    } else if (b < 776) {                // W1 [256d][1024h] -> w1t[e][h][d]
        int bb = b - 264;
        int e = bb >> 6, tj = bb & 63;
        int rt = tj >> 4, ct = tj & 15;
        trans_load(W1 + (size_t)e * D_DIM * H_DIM, H_DIM, rt, ct, tid, tile);
        __syncthreads();
        u16* outp = w1t + (size_t)e * H_DIM * D_DIM;
        #pragma unroll
        for (int it = 0; it < 2; ++it) {
            int oc = it * 32 + (tid >> 3);
            int r0 = (tid & 7) * 8;
            *(uint4*)(outp + (size_t)(ct * 64 + oc) * D_DIM + rt * 64 + r0) =
                trans_pack(tile, oc, r0);
        }
    } else {                             // W2 [1024h][256d] -> w2t[e][d][h]
        int bb = b - 776;
        int e = bb >> 6, tj = bb & 63;
        int rt = tj >> 2, ct = tj & 3;   // rt over H/64, ct over D/64
        trans_load(W2 + (size_t)e * H_DIM * D_DIM, D_DIM, rt, ct, tid, tile);
        __syncthreads();
        u16* outp = w2t + (size_t)e * D_DIM * H_DIM;
        #pragma unroll
        for (int it = 0; it < 2; ++it) {
            int oc = it * 32 + (tid >> 3);
            int r0 = (tid & 7) * 8;
            *(uint4*)(outp + (size_t)(ct * 64 + oc) * H_DIM + rt * 64 + r0) =
                trans_pack(tile, oc, r0);
        }
    }
}

// ---- K2: GEMM1  M=64,N=64,K=256 (R5-proven staging, xb gather) ----
__global__ __launch_bounds__(256, 2) void gemm1_kernel(
    const u16* __restrict__ xb, const u16* __restrict__ w1t,
    const float* __restrict__ b1, const int* __restrict__ cnt,
    const int* __restrict__ bucket, u16* __restrict__ hw)
{
    __shared__ u16 xs[64 * 264];
    __shared__ u16 w1s[64 * 264];
    __shared__ u16 hs[64 * 72];

    const int b = blockIdx.x;
    const int e = b >> 8, tile = (b >> 4) & 15, hch = b & 15;
    const int n = min(cnt[e], CAP);
    const int row0 = tile * 64;
    if (row0 >= n) return;

    const int tid = threadIdx.x;
    const int w = tid >> 6, L = tid & 63, l15 = L & 15, l4 = L >> 4;
    const int wr = (w >> 1) * 32, wc = (w & 1) * 32;

    {
        const int rr = tid >> 5, cc = (tid & 31) * 8;
        // hoist token indices (8 independent loads, no dependent-load serialization)
        int tok[8];
        #pragma unroll
        for (int it = 0; it < 8; ++it) {
            int grow = row0 + it * 8 + rr;
            tok[it] = grow < n ? bucket[e * B_TOK + grow] : 0;   // xb[0] is finite
        }
        const u16* gw = w1t + ((size_t)e * H_DIM + hch * 64) * D_DIM;
        #pragma unroll
        for (int it = 0; it < 8; ++it) {
            int row = it * 8 + rr;
            *(short8*)&xs[row * 264 + cc]  = *(const short8*)&xb[(size_t)tok[it] * D_DIM + cc];
            *(short8*)&w1s[row * 264 + cc] = *(const short8*)&gw[(size_t)row * D_DIM + cc];
        }
    }
    __syncthreads();

    f32x4 acc[2][2];
    #pragma unroll
    for (int i = 0; i < 2; ++i)
        #pragma unroll
        for (int j = 0; j < 2; ++j) acc[i][j] = (f32x4){0.f, 0.f, 0.f, 0.f};

    #pragma unroll
    for (int k = 0; k < 8; ++k) {
        short8 a0 = *(const short8*)&xs[(wr + l15) * 264 + k * 32 + l4 * 8];
        short8 a1 = *(const short8*)&xs[(wr + 16 + l15) * 264 + k * 32 + l4 * 8];
        short8 b0 = *(const short8*)&w1s[(wc + l15) * 264 + k * 32 + l4 * 8];
        short8 b1v = *(const short8*)&w1s[(wc + 16 + l15) * 264 + k * 32 + l4 * 8];
        acc[0][0] = __builtin_amdgcn_mfma_f32_16x16x32_bf16(a0, b0, acc[0][0], 0, 0, 0);
        acc[0][1] = __builtin_amdgcn_mfma_f32_16x16x32_bf16(a0, b1v, acc[0][1], 0, 0, 0);
        acc[1][0] = __builtin_amdgcn_mfma_f32_16x16x32_bf16(a1, b0, acc[1][0], 0, 0, 0);
        acc[1][1] = __builtin_amdgcn_mfma_f32_16x16x32_bf16(a1, b1v, acc[1][1], 0, 0, 0);
    }

    #pragma unroll
    for (int mr = 0; mr < 2; ++mr)
        #pragma unroll
        for (int nc = 0; nc < 2; ++nc) {
            float bias = b1[e * H_DIM + hch * 64 + wc + nc * 16 + l15];
            #pragma unroll
            for (int j = 0; j < 4; ++j) {
                float v = fmaxf(acc[mr][nc][j] + bias, 0.f);
                hs[(wr + mr * 16 + l4 * 4 + j) * 72 + wc + nc * 16 + l15] = f2bf(v);
            }
        }
    __syncthreads();
    {
        u16* gh = hw + ((size_t)e * CAP + row0) * H_DIM + hch * 64;
        int rr8 = tid >> 3, off = (tid & 7) * 8;
        #pragma unroll
        for (int it = 0; it < 2; ++it) {
            int row = it * 32 + rr8;
            *(short8*)&gh[(size_t)row * H_DIM + off] = *(const short8*)&hs[row * 72 + off];
        }
    }
}

// ---- K3: GEMM2  M=64,N=64,K=1024 (4 chunks) — R5 verbatim ----
__global__ __launch_bounds__(256, 2) void gemm2_kernel(
    const u16* __restrict__ hw, const u16* __restrict__ w2t,
    const float* __restrict__ b2, const int* __restrict__ cnt,
    const int* __restrict__ bucket, float* __restrict__ out)
{
    __shared__ u16 as_[64 * 264];
    __shared__ u16 bs[64 * 264];

    int b = blockIdx.x;
    int e = b >> 6, tile = (b >> 2) & 15, nch = b & 3;
    int n = min(cnt[e], CAP);
    if (tile * 64 >= n) return;

    int tid = threadIdx.x;
    int w = tid >> 6, L = tid & 63, l15 = L & 15, l4 = L >> 4;
    int wr = (w >> 1) * 32, wc = (w & 1) * 32;

    f32x4 acc[2][2];
    #pragma unroll
    for (int i = 0; i < 2; ++i)
        #pragma unroll
        for (int j = 0; j < 2; ++j) acc[i][j] = (f32x4){0.f, 0.f, 0.f, 0.f};

    const u16* ga = hw + ((size_t)e * CAP + tile * 64) * H_DIM;
    const u16* gb = w2t + ((size_t)e * D_DIM + nch * 64) * H_DIM;

    for (int kc = 0; kc < 4; ++kc) {
        __syncthreads();
        int rr = tid >> 5, cc = (tid & 31) * 8;
        #pragma unroll
        for (int it = 0; it < 8; ++it) {
            int row = it * 8 + rr;
            *(short8*)&as_[row * 264 + cc] = *(const short8*)&ga[(size_t)row * H_DIM + kc * 256 + cc];
            *(short8*)&bs[row * 264 + cc]  = *(const short8*)&gb[(size_t)row * H_DIM + kc * 256 + cc];
        }
        __syncthreads();
        #pragma unroll
        for (int k = 0; k < 8; ++k) {
            short8 a0 = *(const short8*)&as_[(wr + l15) * 264 + k * 32 + l4 * 8];
            short8 a1 = *(const short8*)&as_[(wr + 16 + l15) * 264 + k * 32 + l4 * 8];
            short8 b0 = *(const short8*)&bs[(wc + l15) * 264 + k * 32 + l4 * 8];
            short8 b1v = *(const short8*)&bs[(wc + 16 + l15) * 264 + k * 32 + l4 * 8];
            acc[0][0] = __builtin_amdgcn_mfma_f32_16x16x32_bf16(a0, b0, acc[0][0], 0, 0, 0);
            acc[0][1] = __builtin_amdgcn_mfma_f32_16x16x32_bf16(a0, b1v, acc[0][1], 0, 0, 0);
            acc[1][0] = __builtin_amdgcn_mfma_f32_16x16x32_bf16(a1, b0, acc[1][0], 0, 0, 0);
            acc[1][1] = __builtin_amdgcn_mfma_f32_16x16x32_bf16(a1, b1v, acc[1][1], 0, 0, 0);
        }
    }

    #pragma unroll
    for (int mr = 0; mr < 2; ++mr)
        #pragma unroll
        for (int jj = 0; jj < 4; ++jj) {
            int m = wr + mr * 16 + l4 * 4 + jj;
            if (tile * 64 + m < n) {
                int token = bucket[e * B_TOK + tile * 64 + m];
                #pragma unroll
                for (int nc = 0; nc < 2; ++nc) {
                    int d = nch * 64 + wc + nc * 16 + l15;
                    out[(size_t)token * D_DIM + d] = acc[mr][nc][jj] + b2[e * D_DIM + d];
                }
            }
        }
}

extern "C" void kernel_launch(void* const* d_in, const int* in_sizes, int n_in,
                              void* d_out, int out_size, void* d_ws, size_t ws_size,
                              hipStream_t stream) {
    const float* x  = (const float*)d_in[0];
    const float* W1 = (const float*)d_in[1];
    const float* b1 = (const float*)d_in[2];
    const float* W2 = (const float*)d_in[3];
    const float* b2 = (const float*)d_in[4];
    const int* eidx = (const int*)d_in[5];
    float* out = (float*)d_out;

    char* ws = (char*)d_ws;
    int* cnt    = (int*)(ws + CNT_OFF);
    int* bucket = (int*)(ws + BUCKET_OFF);
    u16* xb     = (u16*)(ws + XB_OFF);
    u16* w1t    = (u16*)(ws + W1T_OFF);
    u16* w2t    = (u16*)(ws + W2T_OFF);
    u16* hw     = (u16*)(ws + HW_OFF);

    prep_kernel<<<1288, 256, 0, stream>>>(x, W1, W2, eidx, cnt, bucket, xb, w1t, w2t);
    gemm1_kernel<<<E_NUM * 16 * 16, 256, 0, stream>>>(xb, w1t, b1, cnt, bucket, hw);
    gemm2_kernel<<<E_NUM * 16 * 4, 256, 0, stream>>>(hw, w2t, b2, cnt, bucket, out);
}